// Round 3
// baseline (1579.464 us; speedup 1.0000x reference)
//
#include <hip/hip_runtime.h>
#include <math.h>

#define NN 100000
#define NE 1600000
#define D 64
#define DE 32
#define NB_SCAN ((NN + 255) / 256)   // 391

__device__ __forceinline__ int rfl(int v){ return __builtin_amdgcn_readfirstlane(v); }

__global__ __launch_bounds__(256) void k_deg(const int* __restrict__ dst, int* __restrict__ deg){
  int i = blockIdx.x*256 + threadIdx.x;
  if (i < NE) atomicAdd(&deg[dst[i]], 1);
}

__global__ __launch_bounds__(256) void k_scan_a(const int* __restrict__ deg, int* __restrict__ bsum){
  __shared__ int sh[256];
  int tid = threadIdx.x;
  int i = blockIdx.x*256 + tid;
  sh[tid] = (i < NN) ? deg[i] : 0;
  __syncthreads();
  for (int s = 128; s > 0; s >>= 1){
    if (tid < s) sh[tid] += sh[tid+s];
    __syncthreads();
  }
  if (tid == 0) bsum[blockIdx.x] = sh[0];
}

__global__ __launch_bounds__(512) void k_scan_b(int* __restrict__ bsum, int* __restrict__ rowptr){
  __shared__ int tmp[512];
  int tid = threadIdx.x;
  int v = (tid < NB_SCAN) ? bsum[tid] : 0;
  tmp[tid] = v;
  __syncthreads();
  for (int off = 1; off < 512; off <<= 1){
    int t = (tid >= off) ? tmp[tid-off] : 0;
    __syncthreads();
    tmp[tid] += t;
    __syncthreads();
  }
  if (tid < NB_SCAN) bsum[tid] = tmp[tid] - v;   // exclusive block offsets
  if (tid == 511) rowptr[NN] = tmp[511];         // total = NE
}

__global__ __launch_bounds__(256) void k_scan_c(const int* __restrict__ deg, const int* __restrict__ bsum,
                                                int* __restrict__ rowptr, int* __restrict__ cursor){
  __shared__ int tmp[256];
  int tid = threadIdx.x;
  int i = blockIdx.x*256 + tid;
  int v = (i < NN) ? deg[i] : 0;
  tmp[tid] = v;
  __syncthreads();
  for (int off = 1; off < 256; off <<= 1){
    int t = (tid >= off) ? tmp[tid-off] : 0;
    __syncthreads();
    tmp[tid] += t;
    __syncthreads();
  }
  if (i < NN){
    int excl = tmp[tid] - v + bsum[blockIdx.x];
    rowptr[i] = excl;
    cursor[i] = excl;
  }
}

__global__ __launch_bounds__(256) void k_scatter(const int* __restrict__ srcp, const int* __restrict__ dstp,
                                                 int* __restrict__ cursor,
                                                 int* __restrict__ slot, int* __restrict__ ssrc){
  int i = blockIdx.x*256 + threadIdx.x;
  if (i < NE){
    int d = dstp[i];
    int pos = atomicAdd(&cursor[d], 1);
    slot[pos] = i;
    ssrc[pos] = srcp[i];
  }
}

// ea_csr[pos][*] = eattr[slot[pos]][*]  (random 128B reads -> streaming writes)
__global__ __launch_bounds__(256) void k_permute(const int* __restrict__ slot,
                                                 const float4* __restrict__ eattr4,
                                                 float4* __restrict__ ea_csr4){
  int i = blockIdx.x*256 + threadIdx.x;   // one float4 per thread; 8 per edge
  if (i < NE*8){
    int e = i >> 3, c = i & 7;
    int se = slot[e];
    ea_csr4[(size_t)e*8 + c] = eattr4[(size_t)se*8 + c];
  }
}

// xl[n][j] = b[j] + sum_k x[n][k] * W[k][j] ; one wave per node, W column in VGPRs
__global__ __launch_bounds__(256) void k_lin(const float* __restrict__ xin, const float* __restrict__ W,
                                             const float* __restrict__ b, float* __restrict__ xl){
  int lane = threadIdx.x & 63;
  int wid = blockIdx.x*(blockDim.x>>6) + (threadIdx.x>>6);
  int nw = gridDim.x*(blockDim.x>>6);
  float wcol[D];
  #pragma unroll
  for (int kk = 0; kk < D; ++kk) wcol[kk] = W[kk*D + lane];
  float bj = b[lane];
  for (int n0 = wid; n0 < NN; n0 += nw){
    int n = rfl(n0);
    const float* xr = xin + (size_t)n*D;
    float acc = bj;
    #pragma unroll
    for (int kk = 0; kk < D; ++kk) acc = fmaf(xr[kk], wcol[kk], acc);
    xl[(size_t)n*D + lane] = acc;
  }
}

#define LEAKY(v) ((v) > 0.f ? (v) : 0.2f*(v))

// Fused per-destination GATv2: logits + softmax + weighted sum in one pass.
// eattr rows come in CSR-sequential order when perm!=0 (ea_csr), else via slot.
__global__ __launch_bounds__(256) void k_fused(const int* __restrict__ rowptr,
                                               const int* __restrict__ ssrc,
                                               const int* __restrict__ slot, int perm,
                                               const float* __restrict__ eab,
                                               const float* __restrict__ We, const float* __restrict__ att,
                                               const float* __restrict__ xl, const float* __restrict__ bias,
                                               float* __restrict__ outp){
  int lane = threadIdx.x & 63;
  int wid = blockIdx.x*(blockDim.x>>6) + (threadIdx.x>>6);
  int nw = gridDim.x*(blockDim.x>>6);
  float wecol[DE];
  #pragma unroll
  for (int kk = 0; kk < DE; ++kk) wecol[kk] = We[kk*D + lane];
  float attj = att[lane];
  float bj = bias[lane];
  for (int n0 = wid; n0 < NN; n0 += nw){
    int n = rfl(n0);
    int st = rowptr[n], en = rowptr[n+1];
    float xd = xl[(size_t)n*D + lane];
    float den = 0.f, acc = 0.f, tsum = 0.f;
    int i = st;
    for (; i + 4 <= en; i += 4){
      int s0 = ssrc[i], s1 = ssrc[i+1], s2 = ssrc[i+2], s3 = ssrc[i+3];
      const float *ea0, *ea1, *ea2, *ea3;
      if (perm){
        ea0 = eab + (size_t)i*DE; ea1 = ea0 + DE; ea2 = ea1 + DE; ea3 = ea2 + DE;
      } else {
        ea0 = eab + (size_t)slot[i]*DE;   ea1 = eab + (size_t)slot[i+1]*DE;
        ea2 = eab + (size_t)slot[i+2]*DE; ea3 = eab + (size_t)slot[i+3]*DE;
      }
      float xs0 = xl[(size_t)s0*D + lane];
      float xs1 = xl[(size_t)s1*D + lane];
      float xs2 = xl[(size_t)s2*D + lane];
      float xs3 = xl[(size_t)s3*D + lane];
      float t0 = 0.f, t1 = 0.f, t2 = 0.f, t3 = 0.f;
      #pragma unroll
      for (int kk = 0; kk < DE; ++kk){
        float w = wecol[kk];
        t0 = fmaf(ea0[kk], w, t0);
        t1 = fmaf(ea1[kk], w, t1);
        t2 = fmaf(ea2[kk], w, t2);
        t3 = fmaf(ea3[kk], w, t3);
      }
      tsum += (t0 + t1) + (t2 + t3);
      float m0 = xs0 + xd + t0;
      float m1 = xs1 + xd + t1;
      float m2 = xs2 + xd + t2;
      float m3 = xs3 + xd + t3;
      m0 = LEAKY(m0); m1 = LEAKY(m1); m2 = LEAKY(m2); m3 = LEAKY(m3);
      float c0 = m0*attj, c1 = m1*attj, c2 = m2*attj, c3 = m3*attj;
      #pragma unroll
      for (int off = 32; off > 0; off >>= 1){
        c0 += __shfl_xor(c0, off, 64);
        c1 += __shfl_xor(c1, off, 64);
        c2 += __shfl_xor(c2, off, 64);
        c3 += __shfl_xor(c3, off, 64);
      }
      float p0 = __expf(c0), p1 = __expf(c1), p2 = __expf(c2), p3 = __expf(c3);
      den += (p0 + p1) + (p2 + p3);
      acc = fmaf(p0, xs0, acc);
      acc = fmaf(p1, xs1, acc);
      acc = fmaf(p2, xs2, acc);
      acc = fmaf(p3, xs3, acc);
    }
    for (; i < en; ++i){
      int s0 = ssrc[i];
      const float* ea0 = perm ? (eab + (size_t)i*DE) : (eab + (size_t)slot[i]*DE);
      float xs0 = xl[(size_t)s0*D + lane];
      float t0 = 0.f;
      #pragma unroll
      for (int kk = 0; kk < DE; ++kk) t0 = fmaf(ea0[kk], wecol[kk], t0);
      tsum += t0;
      float m0 = xs0 + xd + t0;
      m0 = LEAKY(m0);
      float c0 = m0*attj;
      #pragma unroll
      for (int off = 32; off > 0; off >>= 1) c0 += __shfl_xor(c0, off, 64);
      float p0 = __expf(c0);
      den += p0;
      acc = fmaf(p0, xs0, acc);
    }
    // self loop: ea = mean of incoming eattr -> t = tsum / max(deg,1) (linearity)
    float degf = (float)(en - st);
    float ts = tsum / fmaxf(degf, 1.f);
    float ms = xd + xd + ts;
    ms = LEAKY(ms);
    float cs = ms*attj;
    #pragma unroll
    for (int off = 32; off > 0; off >>= 1) cs += __shfl_xor(cs, off, 64);
    float ps = __expf(cs);
    den += ps;
    acc = fmaf(ps, xd, acc);
    outp[(size_t)n*D + lane] = acc/den + bj;
  }
}

extern "C" void kernel_launch(void* const* d_in, const int* in_sizes, int n_in,
                              void* d_out, int out_size, void* d_ws, size_t ws_size,
                              hipStream_t stream){
  const float* x     = (const float*)d_in[0];
  const int*   ei    = (const int*)d_in[1];
  const float* eattr = (const float*)d_in[2];
  const float* W1    = (const float*)d_in[3];
  const float* b1    = (const float*)d_in[4];
  const float* We1   = (const float*)d_in[5];
  const float* att1  = (const float*)d_in[6];
  const float* bias1 = (const float*)d_in[7];
  const float* W2    = (const float*)d_in[8];
  const float* b2    = (const float*)d_in[9];
  const float* We2   = (const float*)d_in[10];
  const float* att2  = (const float*)d_in[11];
  const float* bias2 = (const float*)d_in[12];
  const int* srcp = ei;
  const int* dstp = ei + NE;
  float* out = (float*)d_out;

  char* p = (char*)d_ws;
  size_t off = 0;
  auto alloc = [&](size_t bytes)->char*{
    char* r = p + off; off = (off + bytes + 255) & ~(size_t)255; return r;
  };
  int* deg      = (int*)alloc((size_t)NN*4);
  int* rowptr   = (int*)alloc((size_t)(NN+1)*4);
  int* cursor   = (int*)alloc((size_t)NN*4);
  int* bsum     = (int*)alloc(512*4);
  int* slot     = (int*)alloc((size_t)NE*4);
  int* ssrc     = (int*)alloc((size_t)NE*4);
  float* xl     = (float*)alloc((size_t)NN*D*4);
  float* h      = (float*)alloc((size_t)NN*D*4);
  size_t base_off = off;
  float* ea_csr = (float*)alloc((size_t)NE*DE*4);           // 205 MB
  int use_perm = (base_off + (size_t)NE*DE*4 <= ws_size) ? 1 : 0;

  hipMemsetAsync(deg, 0, (size_t)NN*4, stream);
  k_deg    <<<(NE+255)/256, 256, 0, stream>>>(dstp, deg);
  k_scan_a <<<NB_SCAN, 256, 0, stream>>>(deg, bsum);
  k_scan_b <<<1, 512, 0, stream>>>(bsum, rowptr);
  k_scan_c <<<NB_SCAN, 256, 0, stream>>>(deg, bsum, rowptr, cursor);
  k_scatter<<<(NE+255)/256, 256, 0, stream>>>(srcp, dstp, cursor, slot, ssrc);

  const float* eab = eattr;
  if (use_perm){
    k_permute<<<(NE*8+255)/256, 256, 0, stream>>>(slot, (const float4*)eattr, (float4*)ea_csr);
    eab = ea_csr;
  }

  // layer 1
  k_lin   <<<2048, 256, 0, stream>>>(x, W1, b1, xl);
  k_fused <<<4096, 256, 0, stream>>>(rowptr, ssrc, slot, use_perm, eab, We1, att1, xl, bias1, h);

  // layer 2
  k_lin   <<<2048, 256, 0, stream>>>(h, W2, b2, xl);
  k_fused <<<4096, 256, 0, stream>>>(rowptr, ssrc, slot, use_perm, eab, We2, att2, xl, bias2, out);
}

// Round 4
// 1354.086 us; speedup vs baseline: 1.1664x; 1.1664x over previous
//
#include <hip/hip_runtime.h>
#include <math.h>

#define NN 100000
#define NE 1600000
#define D 64
#define DE 32
#define NB_SCAN ((NN + 255) / 256)   // 391

__device__ __forceinline__ int rfl(int v){ return __builtin_amdgcn_readfirstlane(v); }

#define LEAKY(v) ((v) > 0.f ? (v) : 0.2f*(v))

__global__ __launch_bounds__(256) void k_deg(const int* __restrict__ dst, int* __restrict__ deg){
  int i = blockIdx.x*256 + threadIdx.x;
  if (i < NE) atomicAdd(&deg[dst[i]], 1);
}

__global__ __launch_bounds__(256) void k_scan_a(const int* __restrict__ deg, int* __restrict__ bsum){
  __shared__ int sh[256];
  int tid = threadIdx.x;
  int i = blockIdx.x*256 + tid;
  sh[tid] = (i < NN) ? deg[i] : 0;
  __syncthreads();
  for (int s = 128; s > 0; s >>= 1){
    if (tid < s) sh[tid] += sh[tid+s];
    __syncthreads();
  }
  if (tid == 0) bsum[blockIdx.x] = sh[0];
}

__global__ __launch_bounds__(512) void k_scan_b(int* __restrict__ bsum, int* __restrict__ rowptr){
  __shared__ int tmp[512];
  int tid = threadIdx.x;
  int v = (tid < NB_SCAN) ? bsum[tid] : 0;
  tmp[tid] = v;
  __syncthreads();
  for (int off = 1; off < 512; off <<= 1){
    int t = (tid >= off) ? tmp[tid-off] : 0;
    __syncthreads();
    tmp[tid] += t;
    __syncthreads();
  }
  if (tid < NB_SCAN) bsum[tid] = tmp[tid] - v;
  if (tid == 511) rowptr[NN] = tmp[511];
}

__global__ __launch_bounds__(256) void k_scan_c(const int* __restrict__ deg, const int* __restrict__ bsum,
                                                int* __restrict__ rowptr, int* __restrict__ cursor){
  __shared__ int tmp[256];
  int tid = threadIdx.x;
  int i = blockIdx.x*256 + tid;
  int v = (i < NN) ? deg[i] : 0;
  tmp[tid] = v;
  __syncthreads();
  for (int off = 1; off < 256; off <<= 1){
    int t = (tid >= off) ? tmp[tid-off] : 0;
    __syncthreads();
    tmp[tid] += t;
    __syncthreads();
  }
  if (i < NN){
    int excl = tmp[tid] - v + bsum[blockIdx.x];
    rowptr[i] = excl;
    cursor[i] = excl;
  }
}

// slot[pos]=edge id (for loop_attr), ssrc[pos]=src node, inv[e]=CSR position of edge e
__global__ __launch_bounds__(256) void k_scatter(const int* __restrict__ srcp, const int* __restrict__ dstp,
                                                 int* __restrict__ cursor, int* __restrict__ slot,
                                                 int* __restrict__ ssrc, int* __restrict__ inv){
  int i = blockIdx.x*256 + threadIdx.x;
  if (i < NE){
    int d = dstp[i];
    int pos = atomicAdd(&cursor[d], 1);
    slot[pos] = i;
    ssrc[pos] = srcp[i];
    inv[i] = pos;
  }
}

// loop_attr[n][k] = mean of incoming edge_attr (0 if isolated); graph-only, shared by both layers
__global__ __launch_bounds__(256) void k_loopattr(const int* __restrict__ rowptr, const int* __restrict__ slot,
                                                  const float* __restrict__ eattr, const int* __restrict__ deg,
                                                  float* __restrict__ loop_attr){
  int lane = threadIdx.x & 63;
  int wid = blockIdx.x*(blockDim.x>>6) + (threadIdx.x>>6);
  int nw = gridDim.x*(blockDim.x>>6);
  int k = lane & 31;
  for (int n0 = wid; n0 < NN; n0 += nw){
    int n = rfl(n0);
    int st = rowptr[n], en = rowptr[n+1];
    float acc = 0.f;
    for (int i = st; i < en; ++i){
      int eid = slot[i];
      acc += eattr[(size_t)eid*DE + k];
    }
    float dg = (float)max(en - st, 1);
    if (lane < 32) loop_attr[(size_t)n*DE + k] = acc / dg;
  }
}

// xl[n][j] = b[j] + sum_k x[n][k]*W[k][j]
__global__ __launch_bounds__(256) void k_lin(const float* __restrict__ xin, const float* __restrict__ W,
                                             const float* __restrict__ b, float* __restrict__ xl){
  int lane = threadIdx.x & 63;
  int wid = blockIdx.x*(blockDim.x>>6) + (threadIdx.x>>6);
  int nw = gridDim.x*(blockDim.x>>6);
  float wcol[D];
  #pragma unroll
  for (int kk = 0; kk < D; ++kk) wcol[kk] = W[kk*D + lane];
  float bj = b[lane];
  for (int n0 = wid; n0 < NN; n0 += nw){
    int n = rfl(n0);
    const float* xr = xin + (size_t)n*D;
    float acc = bj;
    #pragma unroll
    for (int kk = 0; kk < D; ++kk) acc = fmaf(xr[kk], wcol[kk], acc);
    xl[(size_t)n*D + lane] = acc;
  }
}

// Edge-parallel logits in ORIGINAL edge order (eattr streams sequentially).
// Writes p=exp(logit) scattered to CSR position inv[e].
__global__ __launch_bounds__(256) void k_logit(const int* __restrict__ srcp, const int* __restrict__ dstp,
                                               const float* __restrict__ eattr,
                                               const float* __restrict__ We, const float* __restrict__ att,
                                               const float* __restrict__ xl, const int* __restrict__ inv,
                                               float* __restrict__ p_csr){
  int lane = threadIdx.x & 63;
  int wid = blockIdx.x*(blockDim.x>>6) + (threadIdx.x>>6);
  int nw = gridDim.x*(blockDim.x>>6);
  float wecol[DE];
  #pragma unroll
  for (int kk = 0; kk < DE; ++kk) wecol[kk] = We[kk*D + lane];
  float attj = att[lane];
  for (int b0 = wid*4; b0 < NE; b0 += nw*4){
    int e0 = rfl(b0);
    if (e0 + 4 <= NE){
      int s0 = srcp[e0], s1 = srcp[e0+1], s2 = srcp[e0+2], s3 = srcp[e0+3];
      int d0 = dstp[e0], d1 = dstp[e0+1], d2 = dstp[e0+2], d3 = dstp[e0+3];
      const float* ea = eattr + (size_t)e0*DE;   // 4 rows, contiguous 512B
      float xs0 = xl[(size_t)s0*D + lane];
      float xs1 = xl[(size_t)s1*D + lane];
      float xs2 = xl[(size_t)s2*D + lane];
      float xs3 = xl[(size_t)s3*D + lane];
      float xd0 = xl[(size_t)d0*D + lane];
      float xd1 = xl[(size_t)d1*D + lane];
      float xd2 = xl[(size_t)d2*D + lane];
      float xd3 = xl[(size_t)d3*D + lane];
      float t0 = 0.f, t1 = 0.f, t2 = 0.f, t3 = 0.f;
      #pragma unroll
      for (int kk = 0; kk < DE; ++kk){
        float w = wecol[kk];
        t0 = fmaf(ea[kk],        w, t0);
        t1 = fmaf(ea[kk + DE],   w, t1);
        t2 = fmaf(ea[kk + 2*DE], w, t2);
        t3 = fmaf(ea[kk + 3*DE], w, t3);
      }
      float m0 = LEAKY(xs0 + xd0 + t0);
      float m1 = LEAKY(xs1 + xd1 + t1);
      float m2 = LEAKY(xs2 + xd2 + t2);
      float m3 = LEAKY(xs3 + xd3 + t3);
      float c0 = m0*attj, c1 = m1*attj, c2 = m2*attj, c3 = m3*attj;
      #pragma unroll
      for (int off = 32; off > 0; off >>= 1){
        c0 += __shfl_xor(c0, off, 64);
        c1 += __shfl_xor(c1, off, 64);
        c2 += __shfl_xor(c2, off, 64);
        c3 += __shfl_xor(c3, off, 64);
      }
      float pv = __expf((lane==0)?c0:(lane==1)?c1:(lane==2)?c2:c3);
      int ipos = 0;
      if (lane < 4) ipos = inv[e0 + lane];
      if (lane < 4) p_csr[ipos] = pv;
    } else {
      for (int e = e0; e < NE; ++e){
        int s = srcp[e], d = dstp[e];
        const float* ea = eattr + (size_t)e*DE;
        float xs = xl[(size_t)s*D + lane];
        float xd = xl[(size_t)d*D + lane];
        float t = 0.f;
        #pragma unroll
        for (int kk = 0; kk < DE; ++kk) t = fmaf(ea[kk], wecol[kk], t);
        float c = LEAKY(xs + xd + t) * attj;
        #pragma unroll
        for (int off = 32; off > 0; off >>= 1) c += __shfl_xor(c, off, 64);
        if (lane == 0) p_csr[inv[e]] = __expf(c);
      }
    }
  }
}

// Node-parallel softmax-normalize + aggregate. p_csr and ssrc are CSR-sequential;
// self-loop via loop_attr@We (linearity).
__global__ __launch_bounds__(256) void k_agg(const int* __restrict__ rowptr, const int* __restrict__ ssrc,
                                             const float* __restrict__ p_csr, const float* __restrict__ loop_attr,
                                             const float* __restrict__ We, const float* __restrict__ att,
                                             const float* __restrict__ xl, const float* __restrict__ bias,
                                             float* __restrict__ outp){
  int lane = threadIdx.x & 63;
  int wid = blockIdx.x*(blockDim.x>>6) + (threadIdx.x>>6);
  int nw = gridDim.x*(blockDim.x>>6);
  float wecol[DE];
  #pragma unroll
  for (int kk = 0; kk < DE; ++kk) wecol[kk] = We[kk*D + lane];
  float attj = att[lane];
  float bj = bias[lane];
  for (int n0 = wid; n0 < NN; n0 += nw){
    int n = rfl(n0);
    int st = rowptr[n], en = rowptr[n+1];
    float xd = xl[(size_t)n*D + lane];
    // self loop
    const float* la = loop_attr + (size_t)n*DE;
    float ts = 0.f;
    #pragma unroll
    for (int kk = 0; kk < DE; ++kk) ts = fmaf(la[kk], wecol[kk], ts);
    float cs = LEAKY(xd + xd + ts) * attj;
    #pragma unroll
    for (int off = 32; off > 0; off >>= 1) cs += __shfl_xor(cs, off, 64);
    float ps = __expf(cs);
    float den = ps;
    float acc = ps * xd;
    int i = st;
    for (; i + 4 <= en; i += 4){
      int s0 = ssrc[i], s1 = ssrc[i+1], s2 = ssrc[i+2], s3 = ssrc[i+3];
      float p0 = p_csr[i], p1 = p_csr[i+1], p2 = p_csr[i+2], p3 = p_csr[i+3];
      float xs0 = xl[(size_t)s0*D + lane];
      float xs1 = xl[(size_t)s1*D + lane];
      float xs2 = xl[(size_t)s2*D + lane];
      float xs3 = xl[(size_t)s3*D + lane];
      den += (p0 + p1) + (p2 + p3);
      acc = fmaf(p0, xs0, acc);
      acc = fmaf(p1, xs1, acc);
      acc = fmaf(p2, xs2, acc);
      acc = fmaf(p3, xs3, acc);
    }
    for (; i < en; ++i){
      int s = ssrc[i];
      float p = p_csr[i];
      float xs = xl[(size_t)s*D + lane];
      den += p;
      acc = fmaf(p, xs, acc);
    }
    outp[(size_t)n*D + lane] = acc/den + bj;
  }
}

extern "C" void kernel_launch(void* const* d_in, const int* in_sizes, int n_in,
                              void* d_out, int out_size, void* d_ws, size_t ws_size,
                              hipStream_t stream){
  const float* x     = (const float*)d_in[0];
  const int*   ei    = (const int*)d_in[1];
  const float* eattr = (const float*)d_in[2];
  const float* W1    = (const float*)d_in[3];
  const float* b1    = (const float*)d_in[4];
  const float* We1   = (const float*)d_in[5];
  const float* att1  = (const float*)d_in[6];
  const float* bias1 = (const float*)d_in[7];
  const float* W2    = (const float*)d_in[8];
  const float* b2    = (const float*)d_in[9];
  const float* We2   = (const float*)d_in[10];
  const float* att2  = (const float*)d_in[11];
  const float* bias2 = (const float*)d_in[12];
  const int* srcp = ei;
  const int* dstp = ei + NE;
  float* out = (float*)d_out;

  char* p = (char*)d_ws;
  size_t off = 0;
  auto alloc = [&](size_t bytes)->char*{
    char* r = p + off; off = (off + bytes + 255) & ~(size_t)255; return r;
  };
  int* deg        = (int*)alloc((size_t)NN*4);
  int* rowptr     = (int*)alloc((size_t)(NN+1)*4);
  int* cursor     = (int*)alloc((size_t)NN*4);
  int* bsum       = (int*)alloc(512*4);
  int* slot       = (int*)alloc((size_t)NE*4);
  int* ssrc       = (int*)alloc((size_t)NE*4);
  int* inv        = (int*)alloc((size_t)NE*4);
  float* loop_attr= (float*)alloc((size_t)NN*DE*4);
  float* xl       = (float*)alloc((size_t)NN*D*4);
  float* h        = (float*)alloc((size_t)NN*D*4);
  float* p_csr    = (float*)alloc((size_t)NE*4);

  hipMemsetAsync(deg, 0, (size_t)NN*4, stream);
  k_deg     <<<(NE+255)/256, 256, 0, stream>>>(dstp, deg);
  k_scan_a  <<<NB_SCAN, 256, 0, stream>>>(deg, bsum);
  k_scan_b  <<<1, 512, 0, stream>>>(bsum, rowptr);
  k_scan_c  <<<NB_SCAN, 256, 0, stream>>>(deg, bsum, rowptr, cursor);
  k_scatter <<<(NE+255)/256, 256, 0, stream>>>(srcp, dstp, cursor, slot, ssrc, inv);
  k_loopattr<<<2048, 256, 0, stream>>>(rowptr, slot, eattr, deg, loop_attr);

  // layer 1
  k_lin   <<<2048, 256, 0, stream>>>(x, W1, b1, xl);
  k_logit <<<4096, 256, 0, stream>>>(srcp, dstp, eattr, We1, att1, xl, inv, p_csr);
  k_agg   <<<2048, 256, 0, stream>>>(rowptr, ssrc, p_csr, loop_attr, We1, att1, xl, bias1, h);

  // layer 2
  k_lin   <<<2048, 256, 0, stream>>>(h, W2, b2, xl);
  k_logit <<<4096, 256, 0, stream>>>(srcp, dstp, eattr, We2, att2, xl, inv, p_csr);
  k_agg   <<<2048, 256, 0, stream>>>(rowptr, ssrc, p_csr, loop_attr, We2, att2, xl, bias2, out);
}

// Round 5
// 1160.926 us; speedup vs baseline: 1.3605x; 1.1664x over previous
//
#include <hip/hip_runtime.h>
#include <math.h>

#define NN 100000
#define NE 1600000
#define D 64
#define DE 32
#define NB_SCAN ((NN + 255) / 256)   // 391

__device__ __forceinline__ int rfl(int v){ return __builtin_amdgcn_readfirstlane(v); }

#define LEAKY(v) ((v) > 0.f ? (v) : 0.2f*(v))

__device__ __forceinline__ unsigned short f2bf(float x){
  unsigned u = __float_as_uint(x);
  unsigned r = (u + 0x7fffu + ((u >> 16) & 1u)) >> 16;
  return (unsigned short)r;
}
__device__ __forceinline__ float bf2f(unsigned short b){
  return __uint_as_float(((unsigned)b) << 16);
}

// cursor doubles as deg accumulator
__global__ __launch_bounds__(256) void k_deg(const int* __restrict__ dst, int* __restrict__ cursor){
  int i = blockIdx.x*256 + threadIdx.x;
  if (i < NE) atomicAdd(&cursor[dst[i]], 1);
}

__global__ __launch_bounds__(256) void k_scan_a(const int* __restrict__ deg, int* __restrict__ bsum){
  __shared__ int sh[256];
  int tid = threadIdx.x;
  int i = blockIdx.x*256 + tid;
  sh[tid] = (i < NN) ? deg[i] : 0;
  __syncthreads();
  for (int s = 128; s > 0; s >>= 1){
    if (tid < s) sh[tid] += sh[tid+s];
    __syncthreads();
  }
  if (tid == 0) bsum[blockIdx.x] = sh[0];
}

__global__ __launch_bounds__(512) void k_scan_b(int* __restrict__ bsum, int* __restrict__ rowptr){
  __shared__ int tmp[512];
  int tid = threadIdx.x;
  int v = (tid < NB_SCAN) ? bsum[tid] : 0;
  tmp[tid] = v;
  __syncthreads();
  for (int off = 1; off < 512; off <<= 1){
    int t = (tid >= off) ? tmp[tid-off] : 0;
    __syncthreads();
    tmp[tid] += t;
    __syncthreads();
  }
  if (tid < NB_SCAN) bsum[tid] = tmp[tid] - v;
  if (tid == 511) rowptr[NN] = tmp[511];
}

// reads cursor (=deg), writes rowptr and resets cursor to the exclusive offset
__global__ __launch_bounds__(256) void k_scan_c(const int* bsum, int* rowptr, int* cursor){
  __shared__ int tmp[256];
  int tid = threadIdx.x;
  int i = blockIdx.x*256 + tid;
  int v = (i < NN) ? cursor[i] : 0;
  tmp[tid] = v;
  __syncthreads();
  for (int off = 1; off < 256; off <<= 1){
    int t = (tid >= off) ? tmp[tid-off] : 0;
    __syncthreads();
    tmp[tid] += t;
    __syncthreads();
  }
  if (i < NN){
    int excl = tmp[tid] - v + bsum[blockIdx.x];
    rowptr[i] = excl;
    cursor[i] = excl;
  }
}

// ssrc[pos]=src node of CSR slot, inv[e]=CSR position of edge e
__global__ __launch_bounds__(256) void k_scatter(const int* __restrict__ srcp, const int* __restrict__ dstp,
                                                 int* __restrict__ cursor,
                                                 int* __restrict__ ssrc, int* __restrict__ inv){
  int i = blockIdx.x*256 + threadIdx.x;
  if (i < NE){
    int d = dstp[i];
    int pos = atomicAdd(&cursor[d], 1);
    ssrc[pos] = srcp[i];
    inv[i] = pos;
  }
}

// Streaming, gather-free: t_csr[inv[e]][j] = bf16( (eattr[e] @ We)[j] )
// eattr sequential; each t row is exactly one 128B line, scatter-written.
__global__ __launch_bounds__(256) void k_t(const float* __restrict__ eattr,
                                           const float* __restrict__ We,
                                           const int* __restrict__ inv,
                                           unsigned short* __restrict__ t_csr){
  int lane = threadIdx.x & 63;
  int wid = blockIdx.x*(blockDim.x>>6) + (threadIdx.x>>6);
  int nw = gridDim.x*(blockDim.x>>6);
  float wecol[DE];
  #pragma unroll
  for (int kk = 0; kk < DE; ++kk) wecol[kk] = We[kk*D + lane];
  for (int b0 = wid*4; b0 < NE; b0 += nw*4){
    int e0 = rfl(b0);
    if (e0 + 4 <= NE){
      const float* ea = eattr + (size_t)e0*DE;   // 512B contiguous, uniform
      float t0 = 0.f, t1 = 0.f, t2 = 0.f, t3 = 0.f;
      #pragma unroll
      for (int kk = 0; kk < DE; ++kk){
        float w = wecol[kk];
        t0 = fmaf(ea[kk],        w, t0);
        t1 = fmaf(ea[kk + DE],   w, t1);
        t2 = fmaf(ea[kk + 2*DE], w, t2);
        t3 = fmaf(ea[kk + 3*DE], w, t3);
      }
      int p0 = inv[e0], p1 = inv[e0+1], p2 = inv[e0+2], p3 = inv[e0+3];
      t_csr[(size_t)p0*D + lane] = f2bf(t0);
      t_csr[(size_t)p1*D + lane] = f2bf(t1);
      t_csr[(size_t)p2*D + lane] = f2bf(t2);
      t_csr[(size_t)p3*D + lane] = f2bf(t3);
    } else {
      for (int e = e0; e < NE; ++e){
        const float* ea = eattr + (size_t)e*DE;
        float t = 0.f;
        #pragma unroll
        for (int kk = 0; kk < DE; ++kk) t = fmaf(ea[kk], wecol[kk], t);
        t_csr[(size_t)inv[e]*D + lane] = f2bf(t);
      }
    }
  }
}

// xl[n][j] = b[j] + sum_k x[n][k]*W[k][j]
__global__ __launch_bounds__(256) void k_lin(const float* __restrict__ xin, const float* __restrict__ W,
                                             const float* __restrict__ b, float* __restrict__ xl){
  int lane = threadIdx.x & 63;
  int wid = blockIdx.x*(blockDim.x>>6) + (threadIdx.x>>6);
  int nw = gridDim.x*(blockDim.x>>6);
  float wcol[D];
  #pragma unroll
  for (int kk = 0; kk < D; ++kk) wcol[kk] = W[kk*D + lane];
  float bj = b[lane];
  for (int n0 = wid; n0 < NN; n0 += nw){
    int n = rfl(n0);
    const float* xr = xin + (size_t)n*D;
    float acc = bj;
    #pragma unroll
    for (int kk = 0; kk < D; ++kk) acc = fmaf(xr[kk], wcol[kk], acc);
    xl[(size_t)n*D + lane] = acc;
  }
}

#define RED64(c) { _Pragma("unroll") for (int off = 32; off > 0; off >>= 1) c += __shfl_xor(c, off, 64); }

// Fused per-destination: logit + softmax + aggregate. Per edge: 1 gather, 1 seq
// bf16 line, adds, reduce, exp, 2 fma. Self-loop via in-register tsum mean.
__global__ __launch_bounds__(256) void k_node(const int* __restrict__ rowptr,
                                              const int* __restrict__ ssrc,
                                              const unsigned short* __restrict__ t_csr,
                                              const float* __restrict__ att,
                                              const float* __restrict__ xl,
                                              const float* __restrict__ bias,
                                              float* __restrict__ outp){
  int lane = threadIdx.x & 63;
  int wid = blockIdx.x*(blockDim.x>>6) + (threadIdx.x>>6);
  int nw = gridDim.x*(blockDim.x>>6);
  float attj = att[lane];
  float bj = bias[lane];
  for (int n0 = wid; n0 < NN; n0 += nw){
    int n = rfl(n0);
    int st = rowptr[n], en = rowptr[n+1];
    float xd = xl[(size_t)n*D + lane];
    float tsum = 0.f;
    float den0 = 0.f, den1 = 0.f, acc0 = 0.f, acc1 = 0.f;
    int i = st;
    for (; i + 4 <= en; i += 4){
      int s0 = ssrc[i], s1 = ssrc[i+1], s2 = ssrc[i+2], s3 = ssrc[i+3];
      float t0 = bf2f(t_csr[(size_t)i*D + lane]);
      float t1 = bf2f(t_csr[(size_t)(i+1)*D + lane]);
      float t2 = bf2f(t_csr[(size_t)(i+2)*D + lane]);
      float t3 = bf2f(t_csr[(size_t)(i+3)*D + lane]);
      float xs0 = xl[(size_t)s0*D + lane];
      float xs1 = xl[(size_t)s1*D + lane];
      float xs2 = xl[(size_t)s2*D + lane];
      float xs3 = xl[(size_t)s3*D + lane];
      tsum += (t0 + t1) + (t2 + t3);
      float c0 = LEAKY(xs0 + xd + t0) * attj;
      float c1 = LEAKY(xs1 + xd + t1) * attj;
      float c2 = LEAKY(xs2 + xd + t2) * attj;
      float c3 = LEAKY(xs3 + xd + t3) * attj;
      #pragma unroll
      for (int off = 32; off > 0; off >>= 1){
        c0 += __shfl_xor(c0, off, 64);
        c1 += __shfl_xor(c1, off, 64);
        c2 += __shfl_xor(c2, off, 64);
        c3 += __shfl_xor(c3, off, 64);
      }
      float p0 = __expf(c0), p1 = __expf(c1), p2 = __expf(c2), p3 = __expf(c3);
      den0 += p0 + p1;
      den1 += p2 + p3;
      acc0 = fmaf(p0, xs0, acc0);
      acc0 = fmaf(p1, xs1, acc0);
      acc1 = fmaf(p2, xs2, acc1);
      acc1 = fmaf(p3, xs3, acc1);
    }
    for (; i < en; ++i){
      int s = ssrc[i];
      float t = bf2f(t_csr[(size_t)i*D + lane]);
      float xs = xl[(size_t)s*D + lane];
      tsum += t;
      float c = LEAKY(xs + xd + t) * attj;
      RED64(c)
      float p = __expf(c);
      den0 += p;
      acc0 = fmaf(p, xs, acc0);
    }
    // self loop: t_self = mean(t_e) by linearity; 0 for isolated nodes
    float degf = (float)(en - st);
    float ts = tsum / fmaxf(degf, 1.f);
    float cs = LEAKY(xd + xd + ts) * attj;
    RED64(cs)
    float ps = __expf(cs);
    float den = den0 + den1 + ps;
    float acc = fmaf(ps, xd, acc0 + acc1);
    outp[(size_t)n*D + lane] = acc/den + bj;
  }
}

extern "C" void kernel_launch(void* const* d_in, const int* in_sizes, int n_in,
                              void* d_out, int out_size, void* d_ws, size_t ws_size,
                              hipStream_t stream){
  const float* x     = (const float*)d_in[0];
  const int*   ei    = (const int*)d_in[1];
  const float* eattr = (const float*)d_in[2];
  const float* W1    = (const float*)d_in[3];
  const float* b1    = (const float*)d_in[4];
  const float* We1   = (const float*)d_in[5];
  const float* att1  = (const float*)d_in[6];
  const float* bias1 = (const float*)d_in[7];
  const float* W2    = (const float*)d_in[8];
  const float* b2    = (const float*)d_in[9];
  const float* We2   = (const float*)d_in[10];
  const float* att2  = (const float*)d_in[11];
  const float* bias2 = (const float*)d_in[12];
  const int* srcp = ei;
  const int* dstp = ei + NE;
  float* out = (float*)d_out;

  char* p = (char*)d_ws;
  size_t off = 0;
  auto alloc = [&](size_t bytes)->char*{
    char* r = p + off; off = (off + bytes + 255) & ~(size_t)255; return r;
  };
  int* rowptr   = (int*)alloc((size_t)(NN+1)*4);
  int* cursor   = (int*)alloc((size_t)NN*4);       // also deg accumulator
  int* bsum     = (int*)alloc(512*4);
  int* ssrc     = (int*)alloc((size_t)NE*4);
  int* inv      = (int*)alloc((size_t)NE*4);
  float* xl     = (float*)alloc((size_t)NN*D*4);   // layer-1 lin out, reused for layer-2
  float* h      = (float*)alloc((size_t)NN*D*4);   // layer-1 output
  unsigned short* t_csr = (unsigned short*)alloc((size_t)NE*D*2);  // 204.8 MB bf16

  hipMemsetAsync(cursor, 0, (size_t)NN*4, stream);
  k_deg     <<<(NE+255)/256, 256, 0, stream>>>(dstp, cursor);
  k_scan_a  <<<NB_SCAN, 256, 0, stream>>>(cursor, bsum);
  k_scan_b  <<<1, 512, 0, stream>>>(bsum, rowptr);
  k_scan_c  <<<NB_SCAN, 256, 0, stream>>>(bsum, rowptr, cursor);
  k_scatter <<<(NE+255)/256, 256, 0, stream>>>(srcp, dstp, cursor, ssrc, inv);

  // layer 1
  k_t    <<<4096, 256, 0, stream>>>(eattr, We1, inv, t_csr);
  k_lin  <<<2048, 256, 0, stream>>>(x, W1, b1, xl);
  k_node <<<4096, 256, 0, stream>>>(rowptr, ssrc, t_csr, att1, xl, bias1, h);

  // layer 2
  k_t    <<<4096, 256, 0, stream>>>(eattr, We2, inv, t_csr);
  k_lin  <<<2048, 256, 0, stream>>>(h, W2, b2, xl);
  k_node <<<4096, 256, 0, stream>>>(rowptr, ssrc, t_csr, att2, xl, bias2, out);
}

// Round 6
// 708.264 us; speedup vs baseline: 2.2300x; 1.6391x over previous
//
#include <hip/hip_runtime.h>
#include <math.h>

#define NN 100000
#define NE 1600000
#define D 64
#define DE 32
#define NB_SCAN ((NN + 255) / 256)   // 391

typedef __attribute__((ext_vector_type(8))) short short8;
typedef __attribute__((ext_vector_type(4))) float f32x4;

__device__ __forceinline__ int rfl(int v){ return __builtin_amdgcn_readfirstlane(v); }

#define LEAKY(v) ((v) > 0.f ? (v) : 0.2f*(v))

__device__ __forceinline__ unsigned short f2bf(float x){
  unsigned u = __float_as_uint(x);
  unsigned r = (u + 0x7fffu + ((u >> 16) & 1u)) >> 16;
  return (unsigned short)r;
}
__device__ __forceinline__ float bf2f(unsigned short b){
  return __uint_as_float(((unsigned)b) << 16);
}

// cursor doubles as deg accumulator
__global__ __launch_bounds__(256) void k_deg(const int* __restrict__ dst, int* __restrict__ cursor){
  int i = blockIdx.x*256 + threadIdx.x;
  if (i < NE) atomicAdd(&cursor[dst[i]], 1);
}

__global__ __launch_bounds__(256) void k_scan_a(const int* __restrict__ deg, int* __restrict__ bsum){
  __shared__ int sh[256];
  int tid = threadIdx.x;
  int i = blockIdx.x*256 + tid;
  sh[tid] = (i < NN) ? deg[i] : 0;
  __syncthreads();
  for (int s = 128; s > 0; s >>= 1){
    if (tid < s) sh[tid] += sh[tid+s];
    __syncthreads();
  }
  if (tid == 0) bsum[blockIdx.x] = sh[0];
}

__global__ __launch_bounds__(512) void k_scan_b(int* __restrict__ bsum, int* __restrict__ rowptr){
  __shared__ int tmp[512];
  int tid = threadIdx.x;
  int v = (tid < NB_SCAN) ? bsum[tid] : 0;
  tmp[tid] = v;
  __syncthreads();
  for (int off = 1; off < 512; off <<= 1){
    int t = (tid >= off) ? tmp[tid-off] : 0;
    __syncthreads();
    tmp[tid] += t;
    __syncthreads();
  }
  if (tid < NB_SCAN) bsum[tid] = tmp[tid] - v;
  if (tid == 511) rowptr[NN] = tmp[511];
}

// reads cursor (=deg), writes rowptr and resets cursor to the exclusive offset
__global__ __launch_bounds__(256) void k_scan_c(const int* bsum, int* rowptr, int* cursor){
  __shared__ int tmp[256];
  int tid = threadIdx.x;
  int i = blockIdx.x*256 + tid;
  int v = (i < NN) ? cursor[i] : 0;
  tmp[tid] = v;
  __syncthreads();
  for (int off = 1; off < 256; off <<= 1){
    int t = (tid >= off) ? tmp[tid-off] : 0;
    __syncthreads();
    tmp[tid] += t;
    __syncthreads();
  }
  if (i < NN){
    int excl = tmp[tid] - v + bsum[blockIdx.x];
    rowptr[i] = excl;
    cursor[i] = excl;
  }
}

// slot[pos]=edge id of CSR slot, ssrc[pos]=src node of CSR slot
__global__ __launch_bounds__(256) void k_scatter(const int* __restrict__ srcp, const int* __restrict__ dstp,
                                                 int* __restrict__ cursor,
                                                 int* __restrict__ slot, int* __restrict__ ssrc){
  int i = blockIdx.x*256 + threadIdx.x;
  if (i < NE){
    int d = dstp[i];
    int pos = atomicAdd(&cursor[d], 1);
    slot[pos] = i;
    ssrc[pos] = srcp[i];
  }
}

// t_csr[i][j] = bf16( (eattr[slot[i]] @ We)[j] )  via mfma_f32_16x16x32_bf16.
// One wave per 16 CSR slots. Random 128B-aligned row reads (vector loads),
// sequential writes. Optionally computes layer-2's t in the same pass.
__global__ __launch_bounds__(256) void k_t(const float* __restrict__ eattr,
                                           const int* __restrict__ slot,
                                           const float* __restrict__ We1,
                                           const float* __restrict__ We2,
                                           unsigned short* __restrict__ t1,
                                           unsigned short* __restrict__ t2){
  int lane = threadIdx.x & 63;
  int wid = blockIdx.x*(blockDim.x>>6) + (threadIdx.x>>6);
  int nw = gridDim.x*(blockDim.x>>6);
  int r = lane & 15;    // A: edge row within tile; B/D: output col within 16-tile
  int g = lane >> 4;    // k-group (A/B), row-group (D)
  // B fragments: wb[t][i] = We[(8g+i)][16t + r]
  short8 wb1[4], wb2[4];
  #pragma unroll
  for (int t = 0; t < 4; ++t){
    #pragma unroll
    for (int i = 0; i < 8; ++i){
      wb1[t][i] = (short)f2bf(We1[(8*g + i)*D + 16*t + r]);
      wb2[t][i] = (short)f2bf(We2 ? We2[(8*g + i)*D + 16*t + r] : 0.f);
    }
  }
  for (int i0 = wid*16; i0 < NE; i0 += nw*16){
    int sl = slot[i0 + r];
    const float* ea = eattr + (size_t)sl*DE + 8*g;
    float4 q0 = *(const float4*)(ea);
    float4 q1 = *(const float4*)(ea + 4);
    short8 a;
    a[0]=(short)f2bf(q0.x); a[1]=(short)f2bf(q0.y); a[2]=(short)f2bf(q0.z); a[3]=(short)f2bf(q0.w);
    a[4]=(short)f2bf(q1.x); a[5]=(short)f2bf(q1.y); a[6]=(short)f2bf(q1.z); a[7]=(short)f2bf(q1.w);
    f32x4 d0={0.f,0.f,0.f,0.f}, d1={0.f,0.f,0.f,0.f}, d2={0.f,0.f,0.f,0.f}, d3={0.f,0.f,0.f,0.f};
    d0 = __builtin_amdgcn_mfma_f32_16x16x32_bf16(a, wb1[0], d0, 0, 0, 0);
    d1 = __builtin_amdgcn_mfma_f32_16x16x32_bf16(a, wb1[1], d1, 0, 0, 0);
    d2 = __builtin_amdgcn_mfma_f32_16x16x32_bf16(a, wb1[2], d2, 0, 0, 0);
    d3 = __builtin_amdgcn_mfma_f32_16x16x32_bf16(a, wb1[3], d3, 0, 0, 0);
    size_t rb = (size_t)(i0 + 4*g)*D + r;   // row 4g+i, col 16t+r
    #pragma unroll
    for (int i = 0; i < 4; ++i){
      t1[rb + (size_t)i*D +  0] = f2bf(d0[i]);
      t1[rb + (size_t)i*D + 16] = f2bf(d1[i]);
      t1[rb + (size_t)i*D + 32] = f2bf(d2[i]);
      t1[rb + (size_t)i*D + 48] = f2bf(d3[i]);
    }
    if (t2){
      f32x4 e0={0.f,0.f,0.f,0.f}, e1={0.f,0.f,0.f,0.f}, e2={0.f,0.f,0.f,0.f}, e3={0.f,0.f,0.f,0.f};
      e0 = __builtin_amdgcn_mfma_f32_16x16x32_bf16(a, wb2[0], e0, 0, 0, 0);
      e1 = __builtin_amdgcn_mfma_f32_16x16x32_bf16(a, wb2[1], e1, 0, 0, 0);
      e2 = __builtin_amdgcn_mfma_f32_16x16x32_bf16(a, wb2[2], e2, 0, 0, 0);
      e3 = __builtin_amdgcn_mfma_f32_16x16x32_bf16(a, wb2[3], e3, 0, 0, 0);
      #pragma unroll
      for (int i = 0; i < 4; ++i){
        t2[rb + (size_t)i*D +  0] = f2bf(e0[i]);
        t2[rb + (size_t)i*D + 16] = f2bf(e1[i]);
        t2[rb + (size_t)i*D + 32] = f2bf(e2[i]);
        t2[rb + (size_t)i*D + 48] = f2bf(e3[i]);
      }
    }
  }
}

// xl[n][j] = b[j] + sum_k x[n][k]*W[k][j]
__global__ __launch_bounds__(256) void k_lin(const float* __restrict__ xin, const float* __restrict__ W,
                                             const float* __restrict__ b, float* __restrict__ xl){
  int lane = threadIdx.x & 63;
  int wid = blockIdx.x*(blockDim.x>>6) + (threadIdx.x>>6);
  int nw = gridDim.x*(blockDim.x>>6);
  float wcol[D];
  #pragma unroll
  for (int kk = 0; kk < D; ++kk) wcol[kk] = W[kk*D + lane];
  float bj = b[lane];
  for (int n0 = wid; n0 < NN; n0 += nw){
    int n = rfl(n0);
    const float* xr = xin + (size_t)n*D;
    float acc = bj;
    #pragma unroll
    for (int kk = 0; kk < D; ++kk) acc = fmaf(xr[kk], wcol[kk], acc);
    xl[(size_t)n*D + lane] = acc;
  }
}

#define RED64(c) { _Pragma("unroll") for (int off = 32; off > 0; off >>= 1) c += __shfl_xor(c, off, 64); }

// Fused per-destination: logit + softmax + aggregate. Self-loop via in-register tsum mean.
__global__ __launch_bounds__(256) void k_node(const int* __restrict__ rowptr,
                                              const int* __restrict__ ssrc,
                                              const unsigned short* __restrict__ t_csr,
                                              const float* __restrict__ att,
                                              const float* __restrict__ xl,
                                              const float* __restrict__ bias,
                                              float* __restrict__ outp){
  int lane = threadIdx.x & 63;
  int wid = blockIdx.x*(blockDim.x>>6) + (threadIdx.x>>6);
  int nw = gridDim.x*(blockDim.x>>6);
  float attj = att[lane];
  float bj = bias[lane];
  for (int n0 = wid; n0 < NN; n0 += nw){
    int n = rfl(n0);
    int st = rowptr[n], en = rowptr[n+1];
    float xd = xl[(size_t)n*D + lane];
    float tsum = 0.f;
    float den0 = 0.f, den1 = 0.f, acc0 = 0.f, acc1 = 0.f;
    int i = st;
    for (; i + 4 <= en; i += 4){
      int s0 = ssrc[i], s1 = ssrc[i+1], s2 = ssrc[i+2], s3 = ssrc[i+3];
      float t0 = bf2f(t_csr[(size_t)i*D + lane]);
      float t1 = bf2f(t_csr[(size_t)(i+1)*D + lane]);
      float t2 = bf2f(t_csr[(size_t)(i+2)*D + lane]);
      float t3 = bf2f(t_csr[(size_t)(i+3)*D + lane]);
      float xs0 = xl[(size_t)s0*D + lane];
      float xs1 = xl[(size_t)s1*D + lane];
      float xs2 = xl[(size_t)s2*D + lane];
      float xs3 = xl[(size_t)s3*D + lane];
      tsum += (t0 + t1) + (t2 + t3);
      float c0 = LEAKY(xs0 + xd + t0) * attj;
      float c1 = LEAKY(xs1 + xd + t1) * attj;
      float c2 = LEAKY(xs2 + xd + t2) * attj;
      float c3 = LEAKY(xs3 + xd + t3) * attj;
      #pragma unroll
      for (int off = 32; off > 0; off >>= 1){
        c0 += __shfl_xor(c0, off, 64);
        c1 += __shfl_xor(c1, off, 64);
        c2 += __shfl_xor(c2, off, 64);
        c3 += __shfl_xor(c3, off, 64);
      }
      float p0 = __expf(c0), p1 = __expf(c1), p2 = __expf(c2), p3 = __expf(c3);
      den0 += p0 + p1;
      den1 += p2 + p3;
      acc0 = fmaf(p0, xs0, acc0);
      acc0 = fmaf(p1, xs1, acc0);
      acc1 = fmaf(p2, xs2, acc1);
      acc1 = fmaf(p3, xs3, acc1);
    }
    for (; i < en; ++i){
      int s = ssrc[i];
      float t = bf2f(t_csr[(size_t)i*D + lane]);
      float xs = xl[(size_t)s*D + lane];
      tsum += t;
      float c = LEAKY(xs + xd + t) * attj;
      RED64(c)
      float p = __expf(c);
      den0 += p;
      acc0 = fmaf(p, xs, acc0);
    }
    // self loop: t_self = mean(t_e) by linearity; 0 for isolated nodes
    float degf = (float)(en - st);
    float ts = tsum / fmaxf(degf, 1.f);
    float cs = LEAKY(xd + xd + ts) * attj;
    RED64(cs)
    float ps = __expf(cs);
    float den = den0 + den1 + ps;
    float acc = fmaf(ps, xd, acc0 + acc1);
    outp[(size_t)n*D + lane] = acc/den + bj;
  }
}

extern "C" void kernel_launch(void* const* d_in, const int* in_sizes, int n_in,
                              void* d_out, int out_size, void* d_ws, size_t ws_size,
                              hipStream_t stream){
  const float* x     = (const float*)d_in[0];
  const int*   ei    = (const int*)d_in[1];
  const float* eattr = (const float*)d_in[2];
  const float* W1    = (const float*)d_in[3];
  const float* b1    = (const float*)d_in[4];
  const float* We1   = (const float*)d_in[5];
  const float* att1  = (const float*)d_in[6];
  const float* bias1 = (const float*)d_in[7];
  const float* W2    = (const float*)d_in[8];
  const float* b2    = (const float*)d_in[9];
  const float* We2   = (const float*)d_in[10];
  const float* att2  = (const float*)d_in[11];
  const float* bias2 = (const float*)d_in[12];
  const int* srcp = ei;
  const int* dstp = ei + NE;
  float* out = (float*)d_out;

  char* p = (char*)d_ws;
  size_t off = 0;
  auto alloc = [&](size_t bytes)->char*{
    char* r = p + off; off = (off + bytes + 255) & ~(size_t)255; return r;
  };
  int* rowptr   = (int*)alloc((size_t)(NN+1)*4);
  int* cursor   = (int*)alloc((size_t)NN*4);       // also deg accumulator
  int* bsum     = (int*)alloc(512*4);
  int* slot     = (int*)alloc((size_t)NE*4);
  int* ssrc     = (int*)alloc((size_t)NE*4);
  float* xl     = (float*)alloc((size_t)NN*D*4);
  float* h      = (float*)alloc((size_t)NN*D*4);
  unsigned short* t1 = (unsigned short*)alloc((size_t)NE*D*2);  // 204.8 MB
  size_t need_dual = off + (size_t)NE*D*2;
  unsigned short* t2 = (ws_size >= need_dual) ? (unsigned short*)alloc((size_t)NE*D*2) : nullptr;

  hipMemsetAsync(cursor, 0, (size_t)NN*4, stream);
  k_deg     <<<(NE+255)/256, 256, 0, stream>>>(dstp, cursor);
  k_scan_a  <<<NB_SCAN, 256, 0, stream>>>(cursor, bsum);
  k_scan_b  <<<1, 512, 0, stream>>>(bsum, rowptr);
  k_scan_c  <<<NB_SCAN, 256, 0, stream>>>(bsum, rowptr, cursor);
  k_scatter <<<(NE+255)/256, 256, 0, stream>>>(srcp, dstp, cursor, slot, ssrc);

  if (t2){
    // one eattr pass computes both layers' edge transforms
    k_t  <<<2048, 256, 0, stream>>>(eattr, slot, We1, We2, t1, t2);
    k_lin <<<2048, 256, 0, stream>>>(x, W1, b1, xl);
    k_node<<<4096, 256, 0, stream>>>(rowptr, ssrc, t1, att1, xl, bias1, h);
    k_lin <<<2048, 256, 0, stream>>>(h, W2, b2, xl);
    k_node<<<4096, 256, 0, stream>>>(rowptr, ssrc, t2, att2, xl, bias2, out);
  } else {
    k_t  <<<2048, 256, 0, stream>>>(eattr, slot, We1, nullptr, t1, nullptr);
    k_lin <<<2048, 256, 0, stream>>>(x, W1, b1, xl);
    k_node<<<4096, 256, 0, stream>>>(rowptr, ssrc, t1, att1, xl, bias1, h);
    k_t  <<<2048, 256, 0, stream>>>(eattr, slot, We2, nullptr, t1, nullptr);
    k_lin <<<2048, 256, 0, stream>>>(h, W2, b2, xl);
    k_node<<<4096, 256, 0, stream>>>(rowptr, ssrc, t1, att2, xl, bias2, out);
  }
}